// Round 5
// baseline (1402.985 us; speedup 1.0000x reference)
//
#include <hip/hip_runtime.h>
#include <stdint.h>

#define FDIM 128
constexpr int EP_NONE = 0, EP_RELU = 1, EP_FILM = 2, EP_LNRELU = 3;

typedef __attribute__((ext_vector_type(8))) short short8v;  // 8 bf16
typedef __attribute__((ext_vector_type(4))) float f32x4;

struct Srcs { const float* p[5]; };
struct WPtrs { const float* p[14]; };

__device__ inline short f2bf(float f) {
  unsigned u = __float_as_uint(f);
  u = (u + 0x7fffu + ((u >> 16) & 1u)) >> 16;
  return (short)u;
}
__device__ inline float bf2f(short s) {
  return __uint_as_float(((unsigned)(unsigned short)s) << 16);
}

// ---------------- CSR build ----------------

__global__ __launch_bounds__(256)
void k_hist(const int* __restrict__ dst, int* __restrict__ cnt, int E) {
  int e = blockIdx.x * 256 + threadIdx.x;
  if (e < E) atomicAdd(&cnt[dst[e]], 1);
}

__global__ __launch_bounds__(1024)
void k_scan_block(const int* __restrict__ cnt, int* __restrict__ scanned,
                  int* __restrict__ partials, int n) {
  __shared__ int sd[1024];
  int tid = threadIdx.x;
  int i = blockIdx.x * 1024 + tid;
  int v = (i < n) ? cnt[i] : 0;
  sd[tid] = v; __syncthreads();
  for (int off = 1; off < 1024; off <<= 1) {
    int t = (tid >= off) ? sd[tid - off] : 0;
    __syncthreads();
    sd[tid] += t;
    __syncthreads();
  }
  if (i < n) scanned[i] = sd[tid] - v;
  if (tid == 1023) partials[blockIdx.x] = sd[1023];
}

__global__ __launch_bounds__(128)
void k_scan_small(const int* __restrict__ partials, int* __restrict__ p2, int nb) {
  __shared__ int sd[128];
  int tid = threadIdx.x;
  int v = (tid < nb) ? partials[tid] : 0;
  sd[tid] = v; __syncthreads();
  for (int off = 1; off < 128; off <<= 1) {
    int t = (tid >= off) ? sd[tid - off] : 0;
    __syncthreads();
    sd[tid] += t;
    __syncthreads();
  }
  p2[tid] = sd[tid] - v;
}

__global__ __launch_bounds__(256)
void k_finalize(const int* __restrict__ scanned, const int* __restrict__ p2,
                int* __restrict__ indptr, int* __restrict__ cursor, int n, int E) {
  int i = blockIdx.x * 256 + threadIdx.x;
  if (i < n) {
    int v = scanned[i] + p2[i >> 10];
    indptr[i] = v;
    cursor[i] = v;
  }
  if (i == 0) indptr[n] = E;
}

__global__ __launch_bounds__(256)
void k_scatter(const int* __restrict__ src, const int* __restrict__ dst,
               int* __restrict__ cursor, int* __restrict__ eids, int E) {
  int e = blockIdx.x * 256 + threadIdx.x;
  if (e < E) {
    int p = atomicAdd(&cursor[dst[e]], 1);
    eids[p] = src[e];
  }
}

// ---------------- aggregation: z = h + segment_sum(h[src], dst) ----------------
// one wave per node; lane covers 2 cols (float2); gather unrolled x4 for MLP

__global__ __launch_bounds__(256)
void k_aggr(const float* __restrict__ h, const int* __restrict__ indptr,
            const int* __restrict__ eids, float* __restrict__ z, int n) {
  int lane = threadIdx.x & 63;
  int node = blockIdx.x * 4 + (threadIdx.x >> 6);
  if (node >= n) return;
  float2 acc = *(const float2*)&h[(size_t)node * FDIM + lane * 2];
  int s = indptr[node], e = indptr[node + 1];
  for (int base = s; base < e; base += 64) {
    int cnt = min(64, e - base);
    int eid = (base + lane < e) ? eids[base + lane] : 0;
    int j = 0;
    for (; j + 4 <= cnt; j += 4) {
      int s0 = __shfl(eid, j, 64);
      int s1 = __shfl(eid, j + 1, 64);
      int s2 = __shfl(eid, j + 2, 64);
      int s3 = __shfl(eid, j + 3, 64);
      float2 v0 = *(const float2*)&h[(size_t)s0 * FDIM + lane * 2];
      float2 v1 = *(const float2*)&h[(size_t)s1 * FDIM + lane * 2];
      float2 v2 = *(const float2*)&h[(size_t)s2 * FDIM + lane * 2];
      float2 v3 = *(const float2*)&h[(size_t)s3 * FDIM + lane * 2];
      acc.x += v0.x + v1.x + v2.x + v3.x;
      acc.y += v0.y + v1.y + v2.y + v3.y;
    }
    for (; j < cnt; ++j) {
      int sn = __shfl(eid, j, 64);
      float2 hv = *(const float2*)&h[(size_t)sn * FDIM + lane * 2];
      acc.x += hv.x; acc.y += hv.y;
    }
  }
  *(float2*)&z[(size_t)node * FDIM + lane * 2] = acc;
}

// ---------------- weight pre-transpose: W[k][c] f32 -> Wt[m][c][k] bf16 hi/lo ----------------
// 14 unit matrices of 128x128; one block per matrix.

__global__ __launch_bounds__(256)
void k_wt(WPtrs wp, short* __restrict__ wtHi, short* __restrict__ wtLo) {
  const int m = blockIdx.x;
  const float* __restrict__ W = wp.p[m];
  const int t = threadIdx.x;
  #pragma unroll
  for (int u = 0; u < 8; ++u) {
    int chunk = t + u * 256;       // 0..2047 = c*16 + kc
    int c = chunk >> 4, kc = chunk & 15;
    short8v hi, lo;
    #pragma unroll
    for (int j = 0; j < 8; ++j) {
      float w = W[(kc * 8 + j) * FDIM + c];
      short h = f2bf(w);
      hi[j] = h;
      lo[j] = f2bf(w - bf2f(h));
    }
    int off = m * 16384 + c * FDIM + kc * 8;
    *(short8v*)(wtHi + off) = hi;
    *(short8v*)(wtLo + off) = lo;
  }
}

// ---------------- MFMA GEMM: out = epi(sum_js A_js @ W[m0+js] + bias) ----------------
// BM=128 (4 waves x 2 stripes of 16 rows), N=128 (8 col-frags), K=128 (4 k-steps).
// No LDS. A: f32 global -> exact bf16 hi/lo split. B: pre-transposed bf16 hi/lo (L2-hot).
// 3-term split (ah*bh + al*bh + ah*bl) => f32-level accuracy.
// C/D layout (m89-verified): col = lane&15, row = 4*(lane>>4) + reg.
// In-place safe (A==out): block reads only rows it later writes.

template<int NSRC, int EPI>
__global__ __launch_bounds__(256)
void k_mfma(Srcs srcs, const short* __restrict__ wtHi, const short* __restrict__ wtLo,
            int m0, const float* __restrict__ bias, float* __restrict__ out, int n,
            const int* __restrict__ bvec, const float* __restrict__ gam,
            const float* __restrict__ bet, int conv,
            const float* __restrict__ lng, const float* __restrict__ lnb) {
  const int tid = threadIdx.x;
  const int lane = tid & 63;
  const int w = tid >> 6;          // wave 0..3
  const int lr = lane & 15;        // A row-in-stripe / B,D col
  const int lg = lane >> 4;        // k-group / D row-group
  const int row0 = blockIdx.x * 128 + w * 32;

  f32x4 acc[2][8];
  #pragma unroll
  for (int s = 0; s < 2; ++s)
    #pragma unroll
    for (int f = 0; f < 8; ++f) acc[s][f] = (f32x4){0.f, 0.f, 0.f, 0.f};

  for (int js = 0; js < NSRC; ++js) {
    const float* __restrict__ A = srcs.p[js];
    const int wbase = (m0 + js) * 16384;
    #pragma unroll
    for (int k0i = 0; k0i < 4; ++k0i) {
      const int k0 = k0i * 32;
      short8v ah[2], al[2];
      #pragma unroll
      for (int s = 0; s < 2; ++s) {
        const int r = row0 + s * 16 + lr;
        float4 v0 = {0.f, 0.f, 0.f, 0.f}, v1 = {0.f, 0.f, 0.f, 0.f};
        if (r < n) {
          const float* Ar = A + (size_t)r * FDIM + k0 + lg * 8;
          v0 = *(const float4*)Ar;
          v1 = *(const float4*)(Ar + 4);
        }
        const float vv[8] = {v0.x, v0.y, v0.z, v0.w, v1.x, v1.y, v1.z, v1.w};
        #pragma unroll
        for (int j = 0; j < 8; ++j) {
          short h = f2bf(vv[j]);
          ah[s][j] = h;
          al[s][j] = f2bf(vv[j] - bf2f(h));
        }
      }
      #pragma unroll
      for (int f = 0; f < 8; ++f) {
        const int boff = wbase + (f * 16 + lr) * FDIM + k0 + lg * 8;
        short8v bh = *(const short8v*)(wtHi + boff);
        short8v bl = *(const short8v*)(wtLo + boff);
        acc[0][f] = __builtin_amdgcn_mfma_f32_16x16x32_bf16(ah[0], bh, acc[0][f], 0, 0, 0);
        acc[1][f] = __builtin_amdgcn_mfma_f32_16x16x32_bf16(ah[1], bh, acc[1][f], 0, 0, 0);
        acc[0][f] = __builtin_amdgcn_mfma_f32_16x16x32_bf16(al[0], bh, acc[0][f], 0, 0, 0);
        acc[1][f] = __builtin_amdgcn_mfma_f32_16x16x32_bf16(al[1], bh, acc[1][f], 0, 0, 0);
        acc[0][f] = __builtin_amdgcn_mfma_f32_16x16x32_bf16(ah[0], bl, acc[0][f], 0, 0, 0);
        acc[1][f] = __builtin_amdgcn_mfma_f32_16x16x32_bf16(ah[1], bl, acc[1][f], 0, 0, 0);
      }
    }
  }

  float bb[8];
  #pragma unroll
  for (int f = 0; f < 8; ++f) bb[f] = bias[f * 16 + lr];

  if constexpr (EPI == EP_LNRELU) {
    float gg[8], bn[8];
    #pragma unroll
    for (int f = 0; f < 8; ++f) { gg[f] = lng[f * 16 + lr]; bn[f] = lnb[f * 16 + lr]; }
    #pragma unroll
    for (int s = 0; s < 2; ++s) {
      float sm[4] = {0.f, 0.f, 0.f, 0.f}, sq[4] = {0.f, 0.f, 0.f, 0.f};
      #pragma unroll
      for (int f = 0; f < 8; ++f)
        #pragma unroll
        for (int i = 0; i < 4; ++i) {
          float v = acc[s][f][i] + bb[f];
          acc[s][f][i] = v;
          sm[i] += v; sq[i] += v * v;
        }
      #pragma unroll
      for (int m = 1; m < 16; m <<= 1)
        #pragma unroll
        for (int i = 0; i < 4; ++i) {
          sm[i] += __shfl_xor(sm[i], m, 64);
          sq[i] += __shfl_xor(sq[i], m, 64);
        }
      #pragma unroll
      for (int i = 0; i < 4; ++i) {
        const int r = row0 + s * 16 + 4 * lg + i;
        const float mu = sm[i] * (1.f / FDIM);
        const float var = sq[i] * (1.f / FDIM) - mu * mu;
        const float rs = rsqrtf(var + 1e-5f);
        if (r < n) {
          #pragma unroll
          for (int f = 0; f < 8; ++f) {
            float o = fmaxf((acc[s][f][i] - mu) * rs * gg[f] + bn[f], 0.f);
            out[(size_t)r * FDIM + f * 16 + lr] = o;
          }
        }
      }
    }
  } else {
    #pragma unroll
    for (int s = 0; s < 2; ++s)
      #pragma unroll
      for (int i = 0; i < 4; ++i) {
        const int r = row0 + s * 16 + 4 * lg + i;
        if (r >= n) continue;
        float g = 1.f, be = 0.f;
        if constexpr (EPI == EP_FILM) {
          int b = bvec[r];
          g = gam[b * 3 + conv];
          be = bet[b * 3 + conv];
        }
        #pragma unroll
        for (int f = 0; f < 8; ++f) {
          float o = acc[s][f][i] + bb[f];
          if constexpr (EPI == EP_RELU) o = fmaxf(o, 0.f);
          if constexpr (EPI == EP_FILM) o = o * g + be;
          out[(size_t)r * FDIM + f * 16 + lr] = o;
        }
      }
  }
}

// ---------------- launch ----------------

extern "C" void kernel_launch(void* const* d_in, const int* in_sizes, int n_in,
                              void* d_out, int out_size, void* d_ws, size_t ws_size,
                              hipStream_t stream) {
  const float* x       = (const float*)d_in[0];
  const int*   eidx    = (const int*)d_in[1];
  const int*   bvec    = (const int*)d_in[2];
  const float* gam     = (const float*)d_in[3];
  const float* bet     = (const float*)d_in[4];
  const float* pre_W0  = (const float*)d_in[5];
  const float* pre_b0  = (const float*)d_in[6];
  const float* pre_W1  = (const float*)d_in[7];
  const float* pre_b1  = (const float*)d_in[8];
  const float* gin_W   = (const float*)d_in[9];
  const float* gin_b   = (const float*)d_in[10];
  const float* post_W0 = (const float*)d_in[11];
  const float* post_b0 = (const float*)d_in[12];
  const float* lng     = (const float*)d_in[13];
  const float* lnb     = (const float*)d_in[14];
  const float* post_W1 = (const float*)d_in[15];
  const float* post_b1 = (const float*)d_in[16];

  const int n = in_sizes[0] / FDIM;
  const int E = in_sizes[1] / 2;
  const int* esrc = eidx;
  const int* edst = eidx + E;
  float* out = (float*)d_out;

  // Workspace: h0..h3 (4*NF f32), CSR ints, wt bf16 hi/lo. zb/tmp alias d_out.
  const size_t NF = (size_t)n * FDIM;
  float* fws = (float*)d_ws;
  float* h0  = fws;
  float* h1  = fws + NF;
  float* h2  = fws + 2 * NF;
  float* h3  = fws + 3 * NF;
  float* zb  = out;
  float* tmp = out;
  int* iws      = (int*)(fws + 4 * NF);
  int* counts   = iws;               // n
  int* scanned  = iws + n;           // n
  int* indptr   = iws + 2 * n;       // n+1
  int* cursor   = iws + 3 * n + 1;   // n
  int* partials = iws + 4 * n + 1;   // 128
  int* p2       = partials + 128;    // 128
  int* eids     = p2 + 128;          // E
  uintptr_t wtb = ((uintptr_t)(eids + E) + 15) & ~(uintptr_t)15;
  short* wtHi = (short*)wtb;         // 14*16384 bf16
  short* wtLo = wtHi + 14 * 16384;

  // weight pre-transpose
  WPtrs wp;
  wp.p[0] = pre_W0;
  wp.p[1] = pre_W1;
  for (int i = 0; i < 6; ++i) wp.p[2 + i] = gin_W + (size_t)i * 16384;
  for (int j = 0; j < 5; ++j) wp.p[8 + j] = post_W0 + (size_t)j * 16384;
  wp.p[13] = post_W1;
  k_wt<<<14, 256, 0, stream>>>(wp, wtHi, wtLo);

  // CSR build (by dst)
  hipMemsetAsync(counts, 0, (size_t)n * sizeof(int), stream);
  k_hist<<<(E + 255) / 256, 256, 0, stream>>>(edst, counts, E);
  const int nb = (n + 1023) / 1024;
  k_scan_block<<<nb, 1024, 0, stream>>>(counts, scanned, partials, n);
  k_scan_small<<<1, 128, 0, stream>>>(partials, p2, nb);
  k_finalize<<<(n + 255) / 256, 256, 0, stream>>>(scanned, p2, indptr, cursor, n, E);
  k_scatter<<<(E + 255) / 256, 256, 0, stream>>>(esrc, edst, cursor, eids, E);

  const int gb = (n + 127) / 128;

  // preprocess MLP: tmp = relu(x@W0+b0); h0 = tmp@W1+b1
  Srcs sx{{x, nullptr, nullptr, nullptr, nullptr}};
  k_mfma<1, EP_RELU><<<gb, 256, 0, stream>>>(sx, wtHi, wtLo, 0, pre_b0, tmp, n,
                                             nullptr, nullptr, nullptr, 0, nullptr, nullptr);
  Srcs st0{{tmp, nullptr, nullptr, nullptr, nullptr}};
  k_mfma<1, EP_NONE><<<gb, 256, 0, stream>>>(st0, wtHi, wtLo, 1, pre_b1, h0, n,
                                             nullptr, nullptr, nullptr, 0, nullptr, nullptr);

  // GIN convs + FiLM
  float* hprev = h0;
  float* houts[3] = {h1, h2, h3};
  for (int i = 0; i < 3; ++i) {
    k_aggr<<<(n + 3) / 4, 256, 0, stream>>>(hprev, indptr, eids, zb, n);
    Srcs sz{{zb, nullptr, nullptr, nullptr, nullptr}};
    k_mfma<1, EP_RELU><<<gb, 256, 0, stream>>>(
        sz, wtHi, wtLo, 2 + 2 * i, gin_b + (size_t)(2 * i) * FDIM, tmp, n,
        nullptr, nullptr, nullptr, 0, nullptr, nullptr);
    Srcs st{{tmp, nullptr, nullptr, nullptr, nullptr}};
    k_mfma<1, EP_FILM><<<gb, 256, 0, stream>>>(
        st, wtHi, wtLo, 3 + 2 * i, gin_b + (size_t)(2 * i + 1) * FDIM, houts[i], n,
        bvec, gam, bet, i, nullptr, nullptr);
    hprev = houts[i];
  }

  // post: tmp = LN+relu(concat@post_W0+b0); out = tmp@post_W1+b1 (in-place)
  Srcs sj{{x, h0, h1, h2, h3}};
  k_mfma<5, EP_LNRELU><<<gb, 256, 0, stream>>>(sj, wtHi, wtLo, 8, post_b0, tmp, n,
                                               nullptr, nullptr, nullptr, 0, lng, lnb);
  Srcs sf{{tmp, nullptr, nullptr, nullptr, nullptr}};
  k_mfma<1, EP_NONE><<<gb, 256, 0, stream>>>(sf, wtHi, wtLo, 13, post_b1, out, n,
                                             nullptr, nullptr, nullptr, 0, nullptr, nullptr);
}